// Round 1
// 1907.899 us; speedup vs baseline: 2.0921x; 2.0921x over previous
//
#include <hip/hip_runtime.h>
#include <math.h>

#define SEQ    720
#define PRED   720
#define CH     321
#define FCUT   200
#define FOUT   400
#define NBATCH 256
#define NTOT   1440
#define KR     400   // stacked rfft rows: 200 cos + 200 (-sin)
#define MC     800   // stacked mixed rows: 400 real + 400 imag

typedef __bf16 bf16;
typedef bf16  bf16x8 __attribute__((ext_vector_type(8)));
typedef float f32x4  __attribute__((ext_vector_type(4)));

static __device__ __forceinline__ f32x4 mfma16(bf16x8 a, bf16x8 b, f32x4 c) {
    return __builtin_amdgcn_mfma_f32_16x16x32_bf16(a, b, c, 0, 0, 0);
}

// ---------------- init: DFT basis matrices (fp32, unchanged) ----------------
__global__ void init_dmat(float* __restrict__ D) {
    int i = blockIdx.x * 256 + threadIdx.x;
    if (i >= KR * SEQ) return;
    int fp = i / SEQ, t = i % SEQ;
    int f = (fp < FCUT) ? fp : (fp - FCUT);
    int p = (f * t) % SEQ;
    float ang = (float)p * (6.28318530717958647692f / (float)SEQ);
    D[i] = (fp < FCUT) ? cosf(ang) : -sinf(ang);
}

__global__ void init_gmat(float* __restrict__ G) {
    int i = blockIdx.x * 256 + threadIdx.x;
    if (i >= SEQ * MC) return;
    int tp = i / MC, kp = i % MC;
    int t = tp + PRED;
    int k = (kp < FOUT) ? kp : (kp - FOUT);
    int p = (k * t) % NTOT;
    float ang = (float)p * (6.28318530717958647692f / (float)NTOT);
    const float s = 2.0f / (float)NTOT;
    float v;
    if (kp < FOUT) v = (k == 0) ? s : (2.0f * s * cosf(ang));
    else           v = (k == 0) ? 0.0f : (-2.0f * s * sinf(ang));
    G[i] = v;
}

// ---------------- stats (unchanged) ----------------
__global__ void stats_kernel(const float* __restrict__ x,
                             float* __restrict__ mean_bc,
                             float* __restrict__ rstd_bc,
                             float* __restrict__ stdev_bc) {
    int i = blockIdx.x * 256 + threadIdx.x;
    if (i >= NBATCH * CH) return;
    int b = i / CH, c = i % CH;
    const float* p = x + (size_t)b * SEQ * CH + c;
    float s = 0.f, ss = 0.f;
    for (int t = 0; t < SEQ; ++t) {
        float v = p[(size_t)t * CH];
        s += v; ss += v * v;
    }
    float mean = s / (float)SEQ;
    float var = fmaxf((ss - s * mean) / (float)(SEQ - 1), 0.f);
    float st = sqrtf(var + 1e-5f);
    mean_bc[i] = mean;
    stdev_bc[i] = st;
    rstd_bc[i] = 1.0f / st;
}

// ---------------- unified split-bf16 MFMA GEMM ----------------
// MODE 0: rfft  C[z=bl][400][CH] = D[400x720] * xnorm[720][CH]   (B = x_enc, per b)
// MODE 1: mix   C[z=c][800][Bc]  = Wstack[800x400] * XT[400][Bc] + bias
// MODE 2: irfft C[z=c][720][Bc]  = G[720x800] * F[800][Bc]
template<int MODE>
__global__ __launch_bounds__(256)
void gemm_mfma(const float* __restrict__ A,   // MODE0: D ; MODE2: G ; MODE1: unused
               const float* __restrict__ Bg,  // MODE0: x_enc ; MODE1: XT ; MODE2: F
               float* __restrict__ Cg,        // MODE0: Xbuf ; MODE1: F ; MODE2: outT
               const float* __restrict__ P0,  // MODE0: mean_bc ; MODE1: Wr
               const float* __restrict__ P1,  // MODE0: rstd_bc ; MODE1: Wi
               const float* __restrict__ P2,  // MODE1: br
               const float* __restrict__ P3,  // MODE1: bi
               int Bc, int b0, int gx, int gy)
{
    const int M   = (MODE == 0) ? KR : (MODE == 1) ? MC : SEQ;
    const int K   = (MODE == 0) ? SEQ : (MODE == 1) ? KR : MC;
    const int N   = (MODE == 0) ? CH : Bc;
    const int ldb = (MODE == 0) ? CH : Bc;
    const int ldc = (MODE == 0) ? CH : Bc;

    // bijective XCD swizzle (m204): same-XCD hw-blocks get consecutive logical ids
    int orig = blockIdx.x;
    int q = (int)gridDim.x >> 3, r = (int)gridDim.x & 7, xcd = orig & 7;
    int id = (xcd < r ? xcd * (q + 1) : r * (q + 1) + (xcd - r) * q) + (orig >> 3);

    const int z   = id / (gx * gy);
    const int rem = id - z * (gx * gy);
    const int my  = rem / gx;
    const int mx  = rem - my * gx;
    const int m0  = mx * 128;
    const int n0  = my * 128;

    const float* Bp = nullptr; float* Cp = nullptr;
    const float* wrc = nullptr; const float* wic = nullptr;
    const float* mnp = nullptr; const float* rsp = nullptr;
    if (MODE == 0) {
        int b = b0 + z;
        Bp  = Bg + (size_t)b * SEQ * CH;
        Cp  = Cg + (size_t)z * KR * CH;
        mnp = P0 + (size_t)b * CH;
        rsp = P1 + (size_t)b * CH;
    } else if (MODE == 1) {
        Bp  = Bg + (size_t)z * KR * Bc;
        Cp  = Cg + (size_t)z * MC * Bc;
        wrc = P0 + (size_t)z * FOUT * FCUT;
        wic = P1 + (size_t)z * FOUT * FCUT;
    } else {
        Bp  = Bg + (size_t)z * MC * Bc;
        Cp  = Cg + (size_t)z * SEQ * Bc;
    }

    // frag-major LDS: [k/8][row][8] -> fragment read = one conflict-free ds_read_b128
    __shared__ bf16 Ah[4][128][8];
    __shared__ bf16 Al[4][128][8];
    __shared__ bf16 Bh[4][128][8];
    __shared__ bf16 Bl[4][128][8];

    const int tid  = threadIdx.x;
    const int row  = tid & 127;     // staging row (A: m, B: n)
    const int half = tid >> 7;      // 0/1 -> k-local 0..15 / 16..31
    const int kloc = half * 16;

    const int lane = tid & 63;
    const int w    = tid >> 6;
    const int wm   = (w & 1) * 64;
    const int wn   = (w >> 1) * 64;
    const int fr   = lane & 15;
    const int kg   = lane >> 4;

    const int mg = m0 + row;
    const int ng = n0 + row;

    float mn = 0.f, rs = 0.f;
    if (MODE == 0 && ng < CH) { mn = mnp[ng]; rs = rsp[ng]; }

    f32x4 acc[4][4];
#pragma unroll
    for (int i = 0; i < 4; ++i)
#pragma unroll
        for (int j = 0; j < 4; ++j) acc[i][j] = (f32x4){0.f, 0.f, 0.f, 0.f};

    const int ksteps = (K + 31) / 32;
    for (int ks = 0; ks < ksteps; ++ks) {
        const int k0 = ks * 32;
        const int kb = k0 + kloc;
        const bool kval = kb < K;   // K%16==0 for all modes -> whole 16-run valid or not

        // ---- stage A (fp32 -> regs) ----
        float av[16];
        if (MODE == 1) {
            if (kval && mg < M) {
                const bool hi2 = mg >= FOUT;
                const int  o   = hi2 ? mg - FOUT : mg;
#pragma unroll
                for (int qd = 0; qd < 4; ++qd) {
                    int k = kb + qd * 4;
                    bool kb2 = k >= FCUT;
                    int  k2  = kb2 ? k - FCUT : k;
                    const float* basep = (hi2 != kb2) ? wic : wrc;
                    float4 v = *(const float4*)(basep + (size_t)o * FCUT + k2);
                    float sgn = (!hi2 && kb2) ? -1.f : 1.f;
                    av[qd * 4 + 0] = sgn * v.x; av[qd * 4 + 1] = sgn * v.y;
                    av[qd * 4 + 2] = sgn * v.z; av[qd * 4 + 3] = sgn * v.w;
                }
            } else {
#pragma unroll
                for (int u = 0; u < 16; ++u) av[u] = 0.f;
            }
        } else {
            if (kval && mg < M) {
                const float* ap = A + (size_t)mg * K + kb;
#pragma unroll
                for (int qd = 0; qd < 4; ++qd) {
                    float4 v = *(const float4*)(ap + qd * 4);
                    av[qd * 4 + 0] = v.x; av[qd * 4 + 1] = v.y;
                    av[qd * 4 + 2] = v.z; av[qd * 4 + 3] = v.w;
                }
            } else {
#pragma unroll
                for (int u = 0; u < 16; ++u) av[u] = 0.f;
            }
        }

        // ---- stage B (fp32 strided scalar loads, coalesced across lanes) ----
        float bv[16];
        if (kval && ng < N) {
            const float* bp = Bp + (size_t)kb * ldb + ng;
            if (MODE == 0) {
#pragma unroll
                for (int u = 0; u < 16; ++u) bv[u] = (bp[(size_t)u * ldb] - mn) * rs;
            } else {
#pragma unroll
                for (int u = 0; u < 16; ++u) bv[u] = bp[(size_t)u * ldb];
            }
        } else {
#pragma unroll
            for (int u = 0; u < 16; ++u) bv[u] = 0.f;
        }

        // ---- split hi/lo and write frag-major LDS (b128, conflict-free) ----
#pragma unroll
        for (int ch = 0; ch < 2; ++ch) {
            bf16x8 ah_, al_, bh_, bl_;
#pragma unroll
            for (int e = 0; e < 8; ++e) {
                float va = av[ch * 8 + e];
                bf16 ha = (bf16)va;
                ah_[e] = ha;
                al_[e] = (bf16)(va - (float)ha);
                float vb = bv[ch * 8 + e];
                bf16 hb = (bf16)vb;
                bh_[e] = hb;
                bl_[e] = (bf16)(vb - (float)hb);
            }
            *(bf16x8*)&Ah[half * 2 + ch][row][0] = ah_;
            *(bf16x8*)&Al[half * 2 + ch][row][0] = al_;
            *(bf16x8*)&Bh[half * 2 + ch][row][0] = bh_;
            *(bf16x8*)&Bl[half * 2 + ch][row][0] = bl_;
        }
        __syncthreads();

        // ---- compute: 16 frags x 3 MFMAs (hh, lh, hl) ----
        bf16x8 a_h[4], a_l[4];
#pragma unroll
        for (int i = 0; i < 4; ++i) {
            a_h[i] = *(const bf16x8*)&Ah[kg][wm + i * 16 + fr][0];
            a_l[i] = *(const bf16x8*)&Al[kg][wm + i * 16 + fr][0];
        }
#pragma unroll
        for (int j = 0; j < 4; ++j) {
            bf16x8 b_h = *(const bf16x8*)&Bh[kg][wn + j * 16 + fr][0];
            bf16x8 b_l = *(const bf16x8*)&Bl[kg][wn + j * 16 + fr][0];
#pragma unroll
            for (int i = 0; i < 4; ++i) {
                acc[i][j] = mfma16(a_h[i], b_h, acc[i][j]);
                acc[i][j] = mfma16(a_l[i], b_h, acc[i][j]);
                acc[i][j] = mfma16(a_h[i], b_l, acc[i][j]);
            }
        }
        __syncthreads();
    }

    // ---- epilogue: C/D layout col=lane&15, row=(lane>>4)*4+reg (m89-verified) ----
#pragma unroll
    for (int i = 0; i < 4; ++i) {
        const int mbase = m0 + wm + i * 16 + kg * 4;
#pragma unroll
        for (int r2 = 0; r2 < 4; ++r2) {
            const int mm = mbase + r2;
            if (mm >= M) continue;
            float bias = 0.f;
            if (MODE == 1)
                bias = (mm < FOUT) ? P2[(size_t)z * FOUT + mm]
                                   : P3[(size_t)z * FOUT + (mm - FOUT)];
#pragma unroll
            for (int j = 0; j < 4; ++j) {
                const int nn = n0 + wn + j * 16 + fr;
                if (nn < N) Cp[(size_t)mm * ldc + nn] = acc[i][j][r2] + bias;
            }
        }
    }
}

// ---------------- T1: Xbuf[b'][f][c] -> XT[c][f][b'] (unchanged) ----------------
__global__ void transpose_bc(const float* __restrict__ in, float* __restrict__ out, int Bc) {
    __shared__ float tile[32][33];
    int f = blockIdx.x;
    int c0 = blockIdx.y * 32, b0 = blockIdx.z * 32;
    int tx = threadIdx.x, ty = threadIdx.y;
#pragma unroll
    for (int j = 0; j < 4; ++j) {
        int bb = b0 + ty + j * 8, cc = c0 + tx;
        if (bb < Bc && cc < CH)
            tile[ty + j * 8][tx] = in[(size_t)bb * KR * CH + (size_t)f * CH + cc];
    }
    __syncthreads();
#pragma unroll
    for (int j = 0; j < 4; ++j) {
        int cc = c0 + ty + j * 8, bb = b0 + tx;
        if (cc < CH && bb < Bc)
            out[(size_t)cc * KR * Bc + (size_t)f * Bc + bb] = tile[tx][ty + j * 8];
    }
}

// ---------------- T3: outT[c][t][b'] -> out[b0+b'][t][c], de-standardize (unchanged) ----------------
__global__ void transpose_out(const float* __restrict__ outT,
                              const float* __restrict__ mean_bc,
                              const float* __restrict__ stdev_bc,
                              float* __restrict__ out, int b0, int Bc) {
    __shared__ float tile[32][33];
    int t = blockIdx.x;
    int c0 = blockIdx.y * 32, bb0 = blockIdx.z * 32;
    int tx = threadIdx.x, ty = threadIdx.y;
#pragma unroll
    for (int j = 0; j < 4; ++j) {
        int cc = c0 + ty + j * 8, bl = bb0 + tx;
        if (cc < CH && bl < Bc)
            tile[ty + j * 8][tx] = outT[(size_t)cc * SEQ * Bc + (size_t)t * Bc + bl];
    }
    __syncthreads();
#pragma unroll
    for (int j = 0; j < 4; ++j) {
        int cc = c0 + tx, bl = bb0 + ty + j * 8;
        if (cc < CH && bl < Bc) {
            int b = b0 + bl;
            size_t si = (size_t)b * CH + cc;
            out[(size_t)b * SEQ * CH + (size_t)t * CH + cc] =
                tile[tx][ty + j * 8] * stdev_bc[si] + mean_bc[si];
        }
    }
}

// ---------------- launch ----------------
extern "C" void kernel_launch(void* const* d_in, const int* in_sizes, int n_in,
                              void* d_out, int out_size, void* d_ws, size_t ws_size,
                              hipStream_t stream) {
    const float* x_enc = (const float*)d_in[0];
    const float* Wr = (const float*)d_in[4];
    const float* Wi = (const float*)d_in[5];
    const float* br = (const float*)d_in[6];
    const float* bi = (const float*)d_in[7];
    float* out = (float*)d_out;

    auto al = [](size_t x) { return (x + 63) & ~(size_t)63; };
    const size_t fixedf = al((size_t)KR * SEQ) + al((size_t)SEQ * MC) + 3 * al((size_t)NBATCH * CH);

    int Bc = NBATCH;
    while (Bc > 1) {
        size_t perb = al((size_t)Bc * KR * CH) * 2 + al((size_t)Bc * MC * CH) + al((size_t)Bc * SEQ * CH);
        if ((fixedf + perb) * sizeof(float) <= ws_size) break;
        Bc >>= 1;
    }

    float* ws = (float*)d_ws;
    size_t oD = 0;
    size_t oG = oD + al((size_t)KR * SEQ);
    size_t oMean = oG + al((size_t)SEQ * MC);
    size_t oRstd = oMean + al((size_t)NBATCH * CH);
    size_t oStd = oRstd + al((size_t)NBATCH * CH);
    size_t oX = oStd + al((size_t)NBATCH * CH);
    size_t oXT = oX + al((size_t)Bc * KR * CH);
    size_t oF = oXT + al((size_t)Bc * KR * CH);
    size_t oOT = oF + al((size_t)Bc * MC * CH);

    init_dmat<<<(KR * SEQ + 255) / 256, 256, 0, stream>>>(ws + oD);
    init_gmat<<<(SEQ * MC + 255) / 256, 256, 0, stream>>>(ws + oG);
    stats_kernel<<<(NBATCH * CH + 255) / 256, 256, 0, stream>>>(x_enc, ws + oMean, ws + oRstd, ws + oStd);

    const int nch = NBATCH / Bc;
    for (int ci = 0; ci < nch; ++ci) {
        int b0 = ci * Bc;

        {   // rfft: M=400 (gx=4), N=321 (gy=3), z=Bc
            int gx = (KR + 127) / 128, gy = (CH + 127) / 128;
            int nb = gx * gy * Bc;
            gemm_mfma<0><<<nb, 256, 0, stream>>>(ws + oD, x_enc, ws + oX,
                                                 ws + oMean, ws + oRstd, nullptr, nullptr,
                                                 Bc, b0, gx, gy);
        }

        dim3 gT1(KR, (CH + 31) / 32, (Bc + 31) / 32);
        transpose_bc<<<gT1, dim3(32, 8), 0, stream>>>(ws + oX, ws + oXT, Bc);

        {   // mix: M=800 (gx=7), N=Bc, z=CH
            int gx = (MC + 127) / 128, gy = (Bc + 127) / 128;
            int nb = gx * gy * CH;
            gemm_mfma<1><<<nb, 256, 0, stream>>>(nullptr, ws + oXT, ws + oF,
                                                 Wr, Wi, br, bi,
                                                 Bc, 0, gx, gy);
        }

        {   // irfft: M=720 (gx=6), N=Bc, z=CH
            int gx = (SEQ + 127) / 128, gy = (Bc + 127) / 128;
            int nb = gx * gy * CH;
            gemm_mfma<2><<<nb, 256, 0, stream>>>(ws + oG, ws + oF, ws + oOT,
                                                 nullptr, nullptr, nullptr, nullptr,
                                                 Bc, 0, gx, gy);
        }

        dim3 gT3(SEQ, (CH + 31) / 32, (Bc + 31) / 32);
        transpose_out<<<gT3, dim3(32, 8), 0, stream>>>(ws + oOT, ws + oMean, ws + oStd, out, b0, Bc);
    }
}

// Round 2
// 1706.635 us; speedup vs baseline: 2.3388x; 1.1179x over previous
//
#include <hip/hip_runtime.h>
#include <math.h>

#define SEQ    720
#define PRED   720
#define CH     321
#define FCUT   200
#define FOUT   400
#define NBATCH 256
#define NTOT   1440
#define KR     400   // stacked rfft rows: 200 cos + 200 (-sin)
#define MC     800   // stacked mixed rows: 400 real + 400 imag

typedef _Float16 f16;
typedef f16   f16x8 __attribute__((ext_vector_type(8)));
typedef float f32x4 __attribute__((ext_vector_type(4)));

static __device__ __forceinline__ f32x4 mfma16(f16x8 a, f16x8 b, f32x4 c) {
    return __builtin_amdgcn_mfma_f32_16x16x32_f16(a, b, c, 0, 0, 0);
}
static __device__ __forceinline__ f16 tof16(float v) { return (f16)v; }
static __device__ __forceinline__ ushort f16bits(f16 h) { return __builtin_bit_cast(unsigned short, h); }
static __device__ __forceinline__ f16 bits2f16(ushort u) { return __builtin_bit_cast(f16, u); }

// ---------------- init: DFT basis, pre-split into fp16 hi/lo planes ----------------
__global__ void init_dmat(f16* __restrict__ Dh, f16* __restrict__ Dl) {
    int i = blockIdx.x * 256 + threadIdx.x;
    if (i >= KR * SEQ) return;
    int fp = i / SEQ, t = i % SEQ;
    int f = (fp < FCUT) ? fp : (fp - FCUT);
    int p = (f * t) % SEQ;
    float ang = (float)p * (6.28318530717958647692f / (float)SEQ);
    float v = (fp < FCUT) ? cosf(ang) : -sinf(ang);
    f16 h = tof16(v);
    Dh[i] = h;
    Dl[i] = tof16(v - (float)h);
}

__global__ void init_gmat(f16* __restrict__ Gh, f16* __restrict__ Gl) {
    int i = blockIdx.x * 256 + threadIdx.x;
    if (i >= SEQ * MC) return;
    int tp = i / MC, kp = i % MC;
    int t = tp + PRED;
    int k = (kp < FOUT) ? kp : (kp - FOUT);
    int p = (k * t) % NTOT;
    float ang = (float)p * (6.28318530717958647692f / (float)NTOT);
    const float s = 2.0f / (float)NTOT;
    float v;
    if (kp < FOUT) v = (k == 0) ? s : (2.0f * s * cosf(ang));
    else           v = (k == 0) ? 0.0f : (-2.0f * s * sinf(ang));
    f16 h = tof16(v);
    Gh[i] = h;
    Gl[i] = tof16(v - (float)h);
}

// ---------------- stats (unchanged) ----------------
__global__ void stats_kernel(const float* __restrict__ x,
                             float* __restrict__ mean_bc,
                             float* __restrict__ rstd_bc,
                             float* __restrict__ stdev_bc) {
    int i = blockIdx.x * 256 + threadIdx.x;
    if (i >= NBATCH * CH) return;
    int b = i / CH, c = i % CH;
    const float* p = x + (size_t)b * SEQ * CH + c;
    float s = 0.f, ss = 0.f;
    for (int t = 0; t < SEQ; ++t) {
        float v = p[(size_t)t * CH];
        s += v; ss += v * v;
    }
    float mean = s / (float)SEQ;
    float var = fmaxf((ss - s * mean) / (float)(SEQ - 1), 0.f);
    float st = sqrtf(var + 1e-5f);
    mean_bc[i] = mean;
    stdev_bc[i] = st;
    rstd_bc[i] = 1.0f / st;
}

// ---------------- unified 2-term fp16-split MFMA GEMM ----------------
// acc = Ah*Bh + Al*Bh  (A carries ~22-bit mantissa, B ~11-bit)
// MODE 0: rfft  X[z=bl][400][CH](f16)   = D[400x720] * xnorm[720][CH]
// MODE 1: mix   F[z=c][800][Bc](f16)    = Wstack[800x400] * XT[400][Bc] + bias
// MODE 2: irfft outT[z=c][720][Bc](f32) = G[720x800] * F[800][Bc]
template<int MODE>
__global__ __launch_bounds__(256)
void gemm_mfma(const f16* __restrict__ Ahg,   // MODE0: Dh ; MODE2: Gh ; MODE1: unused
               const f16* __restrict__ Alg,   // MODE0: Dl ; MODE2: Gl ; MODE1: unused
               const void* __restrict__ Bg,   // MODE0: x_enc(f32) ; MODE1: XT(f16) ; MODE2: F(f16)
               void* __restrict__ Cg,         // MODE0: X(f16) ; MODE1: F(f16) ; MODE2: outT(f32)
               const float* __restrict__ P0,  // MODE0: mean_bc ; MODE1: Wr
               const float* __restrict__ P1,  // MODE0: rstd_bc ; MODE1: Wi
               const float* __restrict__ P2,  // MODE1: br
               const float* __restrict__ P3,  // MODE1: bi
               int Bc, int b0, int gx, int gy)
{
    const int M   = (MODE == 0) ? KR : (MODE == 1) ? MC : SEQ;
    const int K   = (MODE == 0) ? SEQ : (MODE == 1) ? KR : MC;
    const int N   = (MODE == 0) ? CH : Bc;
    const int ldb = (MODE == 0) ? CH : Bc;
    const int ldc = (MODE == 0) ? CH : Bc;

    // bijective XCD swizzle (m204)
    int orig = blockIdx.x;
    int q = (int)gridDim.x >> 3, r = (int)gridDim.x & 7, xcd = orig & 7;
    int id = (xcd < r ? xcd * (q + 1) : r * (q + 1) + (xcd - r) * q) + (orig >> 3);

    const int z   = id / (gx * gy);
    const int rem = id - z * (gx * gy);
    const int my  = rem / gx;
    const int mx  = rem - my * gx;
    const int m0  = mx * 128;
    const int n0  = my * 128;

    const void* Bp = nullptr; void* Cp = nullptr;
    const float* wrc = nullptr; const float* wic = nullptr;
    const float* mnp = nullptr; const float* rsp = nullptr;
    if (MODE == 0) {
        int b = b0 + z;
        Bp  = (const float*)Bg + (size_t)b * SEQ * CH;
        Cp  = (ushort*)Cg + (size_t)z * KR * CH;
        mnp = P0 + (size_t)b * CH;
        rsp = P1 + (size_t)b * CH;
    } else if (MODE == 1) {
        Bp  = (const ushort*)Bg + (size_t)z * KR * Bc;
        Cp  = (ushort*)Cg + (size_t)z * MC * Bc;
        wrc = P0 + (size_t)z * FOUT * FCUT;
        wic = P1 + (size_t)z * FOUT * FCUT;
    } else {
        Bp  = (const ushort*)Bg + (size_t)z * MC * Bc;
        Cp  = (float*)Cg + (size_t)z * SEQ * Bc;
    }

    // frag-major LDS: [k/8][row][8] -> one conflict-free ds_read_b128 per fragment
    __shared__ f16 Ah[4][128][8];
    __shared__ f16 Al[4][128][8];
    __shared__ f16 Bh[4][128][8];

    const int tid  = threadIdx.x;
    const int row  = tid & 127;     // staging row (A: m, B: n)
    const int half = tid >> 7;      // 0/1 -> k-local 0..15 / 16..31
    const int kloc = half * 16;

    const int lane = tid & 63;
    const int w    = tid >> 6;
    const int wm   = (w & 1) * 64;
    const int wn   = (w >> 1) * 64;
    const int fr   = lane & 15;
    const int kg   = lane >> 4;

    const int mg = m0 + row;
    const int ng = n0 + row;

    float mn = 0.f, rs = 0.f;
    if (MODE == 0 && ng < CH) { mn = mnp[ng]; rs = rsp[ng]; }

    f32x4 acc[4][4];
#pragma unroll
    for (int i = 0; i < 4; ++i)
#pragma unroll
        for (int j = 0; j < 4; ++j) acc[i][j] = (f32x4){0.f, 0.f, 0.f, 0.f};

    const int ksteps = (K + 31) / 32;
    for (int ks = 0; ks < ksteps; ++ks) {
        const int kb = ks * 32 + kloc;
        const bool kval = kb < K;   // 16-granular validity (K % 16 == 0 for all modes)

        // ---- stage A: two fp16 planes ----
        if (MODE == 1) {
            // inline split of W (fp32 -> hi/lo fp16), with stack select + sign
            float av[16];
            if (kval && mg < M) {
                const bool hi2 = mg >= FOUT;
                const int  o   = hi2 ? mg - FOUT : mg;
#pragma unroll
                for (int qd = 0; qd < 4; ++qd) {
                    int k = kb + qd * 4;
                    bool kb2 = k >= FCUT;
                    int  k2  = kb2 ? k - FCUT : k;
                    const float* basep = (hi2 != kb2) ? wic : wrc;
                    float4 v = *(const float4*)(basep + (size_t)o * FCUT + k2);
                    float sgn = (!hi2 && kb2) ? -1.f : 1.f;
                    av[qd * 4 + 0] = sgn * v.x; av[qd * 4 + 1] = sgn * v.y;
                    av[qd * 4 + 2] = sgn * v.z; av[qd * 4 + 3] = sgn * v.w;
                }
            } else {
#pragma unroll
                for (int u = 0; u < 16; ++u) av[u] = 0.f;
            }
#pragma unroll
            for (int ch = 0; ch < 2; ++ch) {
                f16x8 ah_, al_;
#pragma unroll
                for (int e = 0; e < 8; ++e) {
                    float va = av[ch * 8 + e];
                    f16 h = tof16(va);
                    ah_[e] = h;
                    al_[e] = tof16(va - (float)h);
                }
                *(f16x8*)&Ah[half * 2 + ch][row][0] = ah_;
                *(f16x8*)&Al[half * 2 + ch][row][0] = al_;
            }
        } else {
            // pre-split planes: straight 16B vector loads
            f16x8 h0, h1, l0, l1;
            if (kval && mg < M) {
                const f16* ph = Ahg + (size_t)mg * K + kb;
                const f16* pl = Alg + (size_t)mg * K + kb;
                h0 = *(const f16x8*)(ph);
                h1 = *(const f16x8*)(ph + 8);
                l0 = *(const f16x8*)(pl);
                l1 = *(const f16x8*)(pl + 8);
            } else {
                h0 = (f16x8)(f16)0; h1 = (f16x8)(f16)0;
                l0 = (f16x8)(f16)0; l1 = (f16x8)(f16)0;
            }
            *(f16x8*)&Ah[half * 2 + 0][row][0] = h0;
            *(f16x8*)&Ah[half * 2 + 1][row][0] = h1;
            *(f16x8*)&Al[half * 2 + 0][row][0] = l0;
            *(f16x8*)&Al[half * 2 + 1][row][0] = l1;
        }

        // ---- stage B: hi plane only ----
        {
            f16x8 b0, b1;
            if (kval && ng < N) {
                if (MODE == 0) {
                    const float* bp = (const float*)Bp + (size_t)kb * ldb + ng;
#pragma unroll
                    for (int u = 0; u < 8; ++u) b0[u] = tof16((bp[(size_t)u * ldb] - mn) * rs);
#pragma unroll
                    for (int u = 0; u < 8; ++u) b1[u] = tof16((bp[(size_t)(u + 8) * ldb] - mn) * rs);
                } else {
                    const ushort* bp = (const ushort*)Bp + (size_t)kb * ldb + ng;
#pragma unroll
                    for (int u = 0; u < 8; ++u) b0[u] = bits2f16(bp[(size_t)u * ldb]);
#pragma unroll
                    for (int u = 0; u < 8; ++u) b1[u] = bits2f16(bp[(size_t)(u + 8) * ldb]);
                }
            } else {
                b0 = (f16x8)(f16)0; b1 = (f16x8)(f16)0;
            }
            *(f16x8*)&Bh[half * 2 + 0][row][0] = b0;
            *(f16x8*)&Bh[half * 2 + 1][row][0] = b1;
        }
        __syncthreads();

        // ---- compute: 16 frags x 2 MFMAs (hh, lh) ----
        f16x8 a_h[4], a_l[4];
#pragma unroll
        for (int i = 0; i < 4; ++i) {
            a_h[i] = *(const f16x8*)&Ah[kg][wm + i * 16 + fr][0];
            a_l[i] = *(const f16x8*)&Al[kg][wm + i * 16 + fr][0];
        }
#pragma unroll
        for (int j = 0; j < 4; ++j) {
            f16x8 b_h = *(const f16x8*)&Bh[kg][wn + j * 16 + fr][0];
#pragma unroll
            for (int i = 0; i < 4; ++i) {
                acc[i][j] = mfma16(a_h[i], b_h, acc[i][j]);
                acc[i][j] = mfma16(a_l[i], b_h, acc[i][j]);
            }
        }
        __syncthreads();
    }

    // ---- epilogue: C/D layout col=lane&15, row=(lane>>4)*4+reg ----
#pragma unroll
    for (int i = 0; i < 4; ++i) {
        const int mbase = m0 + wm + i * 16 + kg * 4;
#pragma unroll
        for (int r2 = 0; r2 < 4; ++r2) {
            const int mm = mbase + r2;
            if (mm >= M) continue;
            float bias = 0.f;
            if (MODE == 1)
                bias = (mm < FOUT) ? P2[(size_t)z * FOUT + mm]
                                   : P3[(size_t)z * FOUT + (mm - FOUT)];
#pragma unroll
            for (int j = 0; j < 4; ++j) {
                const int nn = n0 + wn + j * 16 + fr;
                if (nn < N) {
                    float v = acc[i][j][r2] + bias;
                    if (MODE == 2) ((float*)Cp)[(size_t)mm * ldc + nn] = v;
                    else           ((ushort*)Cp)[(size_t)mm * ldc + nn] = f16bits(tof16(v));
                }
            }
        }
    }
}

// ---------------- T1: X[b'][f][c](u16) -> XT[c][f][b'](u16) ----------------
__global__ void transpose_bc(const ushort* __restrict__ in, ushort* __restrict__ out, int Bc) {
    __shared__ ushort tile[32][34];
    int f = blockIdx.x;
    int c0 = blockIdx.y * 32, b0 = blockIdx.z * 32;
    int tx = threadIdx.x, ty = threadIdx.y;
#pragma unroll
    for (int j = 0; j < 4; ++j) {
        int bb = b0 + ty + j * 8, cc = c0 + tx;
        if (bb < Bc && cc < CH)
            tile[ty + j * 8][tx] = in[(size_t)bb * KR * CH + (size_t)f * CH + cc];
    }
    __syncthreads();
#pragma unroll
    for (int j = 0; j < 4; ++j) {
        int cc = c0 + ty + j * 8, bb = b0 + tx;
        if (cc < CH && bb < Bc)
            out[(size_t)cc * KR * Bc + (size_t)f * Bc + bb] = tile[tx][ty + j * 8];
    }
}

// ---------------- T3: outT[c][t][b'](f32) -> out[b0+b'][t][c], de-standardize ----------------
__global__ void transpose_out(const float* __restrict__ outT,
                              const float* __restrict__ mean_bc,
                              const float* __restrict__ stdev_bc,
                              float* __restrict__ out, int b0, int Bc) {
    __shared__ float tile[32][33];
    int t = blockIdx.x;
    int c0 = blockIdx.y * 32, bb0 = blockIdx.z * 32;
    int tx = threadIdx.x, ty = threadIdx.y;
#pragma unroll
    for (int j = 0; j < 4; ++j) {
        int cc = c0 + ty + j * 8, bl = bb0 + tx;
        if (cc < CH && bl < Bc)
            tile[ty + j * 8][tx] = outT[(size_t)cc * SEQ * Bc + (size_t)t * Bc + bl];
    }
    __syncthreads();
#pragma unroll
    for (int j = 0; j < 4; ++j) {
        int cc = c0 + tx, bl = bb0 + ty + j * 8;
        if (cc < CH && bl < Bc) {
            int b = b0 + bl;
            size_t si = (size_t)b * CH + cc;
            out[(size_t)b * SEQ * CH + (size_t)t * CH + cc] =
                tile[tx][ty + j * 8] * stdev_bc[si] + mean_bc[si];
        }
    }
}

// ---------------- launch ----------------
extern "C" void kernel_launch(void* const* d_in, const int* in_sizes, int n_in,
                              void* d_out, int out_size, void* d_ws, size_t ws_size,
                              hipStream_t stream) {
    const float* x_enc = (const float*)d_in[0];
    const float* Wr = (const float*)d_in[4];
    const float* Wi = (const float*)d_in[5];
    const float* br = (const float*)d_in[6];
    const float* bi = (const float*)d_in[7];
    float* out = (float*)d_out;

    auto alb = [](size_t x) { return (x + 255) & ~(size_t)255; };  // 256B align
    const size_t fixedB = 2 * alb((size_t)KR * SEQ * 2)      // Dh, Dl
                        + 2 * alb((size_t)SEQ * MC * 2)      // Gh, Gl
                        + 3 * alb((size_t)NBATCH * CH * 4);  // mean, rstd, std

    int Bc = NBATCH;
    while (Bc > 1) {
        size_t perB = 2 * alb((size_t)Bc * KR * CH * 2)      // X, XT (f16)
                    + alb((size_t)CH * MC * Bc * 2)          // F (f16)
                    + alb((size_t)CH * SEQ * Bc * 4);        // outT (f32)
        if (fixedB + perB <= ws_size) break;
        Bc >>= 1;
    }

    char* wsb = (char*)d_ws;
    size_t off = 0;
    auto take = [&](size_t bytes) { size_t o = off; off += alb(bytes); return o; };
    f16*    Dh   = (f16*)(wsb + take((size_t)KR * SEQ * 2));
    f16*    Dl   = (f16*)(wsb + take((size_t)KR * SEQ * 2));
    f16*    Gh   = (f16*)(wsb + take((size_t)SEQ * MC * 2));
    f16*    Gl   = (f16*)(wsb + take((size_t)SEQ * MC * 2));
    float*  Mean = (float*)(wsb + take((size_t)NBATCH * CH * 4));
    float*  Rstd = (float*)(wsb + take((size_t)NBATCH * CH * 4));
    float*  Stdv = (float*)(wsb + take((size_t)NBATCH * CH * 4));
    ushort* Xb   = (ushort*)(wsb + take((size_t)Bc * KR * CH * 2));
    ushort* XT   = (ushort*)(wsb + take((size_t)Bc * KR * CH * 2));
    ushort* Fb   = (ushort*)(wsb + take((size_t)CH * MC * Bc * 2));
    float*  OT   = (float*)(wsb + take((size_t)CH * SEQ * Bc * 4));

    init_dmat<<<(KR * SEQ + 255) / 256, 256, 0, stream>>>(Dh, Dl);
    init_gmat<<<(SEQ * MC + 255) / 256, 256, 0, stream>>>(Gh, Gl);
    stats_kernel<<<(NBATCH * CH + 255) / 256, 256, 0, stream>>>(x_enc, Mean, Rstd, Stdv);

    const int nch = NBATCH / Bc;
    for (int ci = 0; ci < nch; ++ci) {
        int b0 = ci * Bc;

        {   // rfft
            int gx = (KR + 127) / 128, gy = (CH + 127) / 128;
            int nb = gx * gy * Bc;
            gemm_mfma<0><<<nb, 256, 0, stream>>>(Dh, Dl, (const void*)x_enc, (void*)Xb,
                                                 Mean, Rstd, nullptr, nullptr,
                                                 Bc, b0, gx, gy);
        }

        dim3 gT1(KR, (CH + 31) / 32, (Bc + 31) / 32);
        transpose_bc<<<gT1, dim3(32, 8), 0, stream>>>(Xb, XT, Bc);

        {   // mix
            int gx = (MC + 127) / 128, gy = (Bc + 127) / 128;
            int nb = gx * gy * CH;
            gemm_mfma<1><<<nb, 256, 0, stream>>>(nullptr, nullptr, (const void*)XT, (void*)Fb,
                                                 Wr, Wi, br, bi,
                                                 Bc, 0, gx, gy);
        }

        {   // irfft
            int gx = (SEQ + 127) / 128, gy = (Bc + 127) / 128;
            int nb = gx * gy * CH;
            gemm_mfma<2><<<nb, 256, 0, stream>>>(Gh, Gl, (const void*)Fb, (void*)OT,
                                                 nullptr, nullptr, nullptr, nullptr,
                                                 Bc, 0, gx, gy);
        }

        dim3 gT3(SEQ, (CH + 31) / 32, (Bc + 31) / 32);
        transpose_out<<<gT3, dim3(32, 8), 0, stream>>>(OT, Mean, Stdv, out, b0, Bc);
    }
}

// Round 3
// 1697.023 us; speedup vs baseline: 2.3521x; 1.0057x over previous
//
#include <hip/hip_runtime.h>
#include <math.h>

#define SEQ    720
#define PRED   720
#define CH     321
#define FCUT   200
#define FOUT   400
#define NBATCH 256
#define NTOT   1440
#define KR     400   // stacked rfft rows: 200 cos + 200 (-sin)
#define MC     800   // stacked mixed rows: 400 real + 400 imag

typedef _Float16 f16;
typedef f16   f16x8 __attribute__((ext_vector_type(8)));
typedef float f32x4 __attribute__((ext_vector_type(4)));

static __device__ __forceinline__ f32x4 mfma16(f16x8 a, f16x8 b, f32x4 c) {
    return __builtin_amdgcn_mfma_f32_16x16x32_f16(a, b, c, 0, 0, 0);
}
static __device__ __forceinline__ f16 tof16(float v) { return (f16)v; }
static __device__ __forceinline__ ushort f16bits(f16 h) { return __builtin_bit_cast(unsigned short, h); }
static __device__ __forceinline__ f16 bits2f16(ushort u) { return __builtin_bit_cast(f16, u); }

// ---------------- init: DFT basis, pre-split into fp16 hi/lo planes ----------------
__global__ void init_dmat(f16* __restrict__ Dh, f16* __restrict__ Dl) {
    int i = blockIdx.x * 256 + threadIdx.x;
    if (i >= KR * SEQ) return;
    int fp = i / SEQ, t = i % SEQ;
    int f = (fp < FCUT) ? fp : (fp - FCUT);
    int p = (f * t) % SEQ;
    float ang = (float)p * (6.28318530717958647692f / (float)SEQ);
    float v = (fp < FCUT) ? cosf(ang) : -sinf(ang);
    f16 h = tof16(v);
    Dh[i] = h;
    Dl[i] = tof16(v - (float)h);
}

__global__ void init_gmat(f16* __restrict__ Gh, f16* __restrict__ Gl) {
    int i = blockIdx.x * 256 + threadIdx.x;
    if (i >= SEQ * MC) return;
    int tp = i / MC, kp = i % MC;
    int t = tp + PRED;
    int k = (kp < FOUT) ? kp : (kp - FOUT);
    int p = (k * t) % NTOT;
    float ang = (float)p * (6.28318530717958647692f / (float)NTOT);
    const float s = 2.0f / (float)NTOT;
    float v;
    if (kp < FOUT) v = (k == 0) ? s : (2.0f * s * cosf(ang));
    else           v = (k == 0) ? 0.0f : (-2.0f * s * sinf(ang));
    f16 h = tof16(v);
    Gh[i] = h;
    Gl[i] = tof16(v - (float)h);
}

// ---------------- stats (unchanged) ----------------
__global__ void stats_kernel(const float* __restrict__ x,
                             float* __restrict__ mean_bc,
                             float* __restrict__ rstd_bc,
                             float* __restrict__ stdev_bc) {
    int i = blockIdx.x * 256 + threadIdx.x;
    if (i >= NBATCH * CH) return;
    int b = i / CH, c = i % CH;
    const float* p = x + (size_t)b * SEQ * CH + c;
    float s = 0.f, ss = 0.f;
    for (int t = 0; t < SEQ; ++t) {
        float v = p[(size_t)t * CH];
        s += v; ss += v * v;
    }
    float mean = s / (float)SEQ;
    float var = fmaxf((ss - s * mean) / (float)(SEQ - 1), 0.f);
    float st = sqrtf(var + 1e-5f);
    mean_bc[i] = mean;
    stdev_bc[i] = st;
    rstd_bc[i] = 1.0f / st;
}

// ---------------- unified 2-term fp16-split MFMA GEMM, prefetch + LDS dbuf ----------------
// acc = Ah*Bh + Al*Bh  (A ~22-bit mantissa, B ~11-bit)
// MODE 0: rfft  X[z=bl][400][CH](f16)   = D[400x720] * xnorm[720][CH]
// MODE 1: mix   F[z=c][800][Bc](f16)    = Wstack[800x400] * XT[400][Bc] + bias
// MODE 2: irfft outT[z=c][720][Bc](f32) = G[720x800] * F[800][Bc]
template<int MODE>
__global__ __launch_bounds__(256)
void gemm_mfma(const f16* __restrict__ Ahg,   // MODE0: Dh ; MODE2: Gh ; MODE1: unused
               const f16* __restrict__ Alg,   // MODE0: Dl ; MODE2: Gl ; MODE1: unused
               const void* __restrict__ Bg,   // MODE0: x_enc(f32) ; MODE1: XT(f16) ; MODE2: F(f16)
               void* __restrict__ Cg,         // MODE0: X(f16) ; MODE1: F(f16) ; MODE2: outT(f32)
               const float* __restrict__ P0,  // MODE0: mean_bc ; MODE1: Wr
               const float* __restrict__ P1,  // MODE0: rstd_bc ; MODE1: Wi
               const float* __restrict__ P2,  // MODE1: br
               const float* __restrict__ P3,  // MODE1: bi
               int Bc, int b0, int gx, int gy)
{
    const int M   = (MODE == 0) ? KR : (MODE == 1) ? MC : SEQ;
    const int K   = (MODE == 0) ? SEQ : (MODE == 1) ? KR : MC;
    const int N   = (MODE == 0) ? CH : Bc;
    const int ldb = (MODE == 0) ? CH : Bc;
    const int ldc = (MODE == 0) ? CH : Bc;

    // bijective XCD swizzle (m204)
    int orig = blockIdx.x;
    int q = (int)gridDim.x >> 3, r = (int)gridDim.x & 7, xcd = orig & 7;
    int id = (xcd < r ? xcd * (q + 1) : r * (q + 1) + (xcd - r) * q) + (orig >> 3);

    const int z   = id / (gx * gy);
    const int rem = id - z * (gx * gy);
    const int my  = rem / gx;
    const int mx  = rem - my * gx;
    const int m0  = mx * 128;
    const int n0  = my * 128;

    const void* Bp = nullptr; void* Cp = nullptr;
    const float* wrc = nullptr; const float* wic = nullptr;
    const float* mnp = nullptr; const float* rsp = nullptr;
    if (MODE == 0) {
        int b = b0 + z;
        Bp  = (const float*)Bg + (size_t)b * SEQ * CH;
        Cp  = (ushort*)Cg + (size_t)z * KR * CH;
        mnp = P0 + (size_t)b * CH;
        rsp = P1 + (size_t)b * CH;
    } else if (MODE == 1) {
        Bp  = (const ushort*)Bg + (size_t)z * KR * Bc;
        Cp  = (ushort*)Cg + (size_t)z * MC * Bc;
        wrc = P0 + (size_t)z * FOUT * FCUT;
        wic = P1 + (size_t)z * FOUT * FCUT;
    } else {
        Bp  = (const ushort*)Bg + (size_t)z * MC * Bc;
        Cp  = (float*)Cg + (size_t)z * SEQ * Bc;
    }

    // double-buffered frag-major LDS: [buf][k/8][row][8]
    __shared__ f16 AhS[2][4][128][8];
    __shared__ f16 AlS[2][4][128][8];
    __shared__ f16 BhS[2][4][128][8];

    const int tid  = threadIdx.x;
    const int row  = tid & 127;     // staging row (A: m, B: n)
    const int half = tid >> 7;      // 0/1 -> k-local 0..15 / 16..31

    const int lane = tid & 63;
    const int w    = tid >> 6;
    const int wm   = (w & 1) * 64;
    const int wn   = (w >> 1) * 64;
    const int fr   = lane & 15;
    const int kg   = lane >> 4;

    const int mg = m0 + row;
    const int ng = n0 + row;

    float mn = 0.f, rs = 0.f;
    if (MODE == 0 && ng < CH) { mn = mnp[ng]; rs = rsp[ng]; }

    f32x4 acc[4][4];
#pragma unroll
    for (int i = 0; i < 4; ++i)
#pragma unroll
        for (int j = 0; j < 4; ++j) acc[i][j] = (f32x4){0.f, 0.f, 0.f, 0.f};

    // prefetch registers
    f16x8 rah0, rah1, ral0, ral1;   // modes 0/2
    float  rav[16];                 // mode 1
    float  rbf[16];                 // mode 0
    ushort rbu[16];                 // modes 1/2

    const int ksteps = (K + 31) / 32;

    auto LOAD = [&](int ks) {
        const int kb = ks * 32 + half * 16;
        const bool kval = kb < K;   // 16-granular validity (K % 16 == 0)
        if (MODE == 1) {
            if (kval && mg < M) {
                const bool hi2 = mg >= FOUT;
                const int  o   = hi2 ? mg - FOUT : mg;
#pragma unroll
                for (int qd = 0; qd < 4; ++qd) {
                    int k = kb + qd * 4;
                    bool kb2 = k >= FCUT;
                    int  k2  = kb2 ? k - FCUT : k;
                    const float* basep = (hi2 != kb2) ? wic : wrc;
                    float4 v = *(const float4*)(basep + (size_t)o * FCUT + k2);
                    float sgn = (!hi2 && kb2) ? -1.f : 1.f;
                    rav[qd * 4 + 0] = sgn * v.x; rav[qd * 4 + 1] = sgn * v.y;
                    rav[qd * 4 + 2] = sgn * v.z; rav[qd * 4 + 3] = sgn * v.w;
                }
            } else {
#pragma unroll
                for (int u = 0; u < 16; ++u) rav[u] = 0.f;
            }
        } else {
            if (kval && mg < M) {
                const f16* ph = Ahg + (size_t)mg * K + kb;
                const f16* pl = Alg + (size_t)mg * K + kb;
                rah0 = *(const f16x8*)(ph);
                rah1 = *(const f16x8*)(ph + 8);
                ral0 = *(const f16x8*)(pl);
                ral1 = *(const f16x8*)(pl + 8);
            } else {
                rah0 = (f16x8)(f16)0; rah1 = (f16x8)(f16)0;
                ral0 = (f16x8)(f16)0; ral1 = (f16x8)(f16)0;
            }
        }
        if (kval && ng < N) {
            if (MODE == 0) {
                const float* bp = (const float*)Bp + (size_t)kb * ldb + ng;
#pragma unroll
                for (int u = 0; u < 16; ++u) rbf[u] = bp[(size_t)u * ldb];
            } else {
                const ushort* bp = (const ushort*)Bp + (size_t)kb * ldb + ng;
#pragma unroll
                for (int u = 0; u < 16; ++u) rbu[u] = bp[(size_t)u * ldb];
            }
        } else {
            if (MODE == 0) {
#pragma unroll
                for (int u = 0; u < 16; ++u) rbf[u] = 0.f;
            } else {
#pragma unroll
                for (int u = 0; u < 16; ++u) rbu[u] = 0;
            }
        }
    };

    auto STORE = [&](int pb) {
        if (MODE == 1) {
#pragma unroll
            for (int ch = 0; ch < 2; ++ch) {
                f16x8 ah_, al_;
#pragma unroll
                for (int e = 0; e < 8; ++e) {
                    float va = rav[ch * 8 + e];
                    f16 h = tof16(va);
                    ah_[e] = h;
                    al_[e] = tof16(va - (float)h);
                }
                *(f16x8*)&AhS[pb][half * 2 + ch][row][0] = ah_;
                *(f16x8*)&AlS[pb][half * 2 + ch][row][0] = al_;
            }
        } else {
            *(f16x8*)&AhS[pb][half * 2 + 0][row][0] = rah0;
            *(f16x8*)&AhS[pb][half * 2 + 1][row][0] = rah1;
            *(f16x8*)&AlS[pb][half * 2 + 0][row][0] = ral0;
            *(f16x8*)&AlS[pb][half * 2 + 1][row][0] = ral1;
        }
        {
            f16x8 b0_, b1_;
            if (MODE == 0) {
#pragma unroll
                for (int u = 0; u < 8; ++u) b0_[u] = tof16((rbf[u] - mn) * rs);
#pragma unroll
                for (int u = 0; u < 8; ++u) b1_[u] = tof16((rbf[u + 8] - mn) * rs);
            } else {
#pragma unroll
                for (int u = 0; u < 8; ++u) b0_[u] = bits2f16(rbu[u]);
#pragma unroll
                for (int u = 0; u < 8; ++u) b1_[u] = bits2f16(rbu[u + 8]);
            }
            *(f16x8*)&BhS[pb][half * 2 + 0][row][0] = b0_;
            *(f16x8*)&BhS[pb][half * 2 + 1][row][0] = b1_;
        }
    };

    auto COMPUTE = [&](int pb) {
        f16x8 a_h[4], a_l[4];
#pragma unroll
        for (int i = 0; i < 4; ++i) {
            a_h[i] = *(const f16x8*)&AhS[pb][kg][wm + i * 16 + fr][0];
            a_l[i] = *(const f16x8*)&AlS[pb][kg][wm + i * 16 + fr][0];
        }
        __builtin_amdgcn_s_setprio(1);
#pragma unroll
        for (int j = 0; j < 4; ++j) {
            f16x8 b_h = *(const f16x8*)&BhS[pb][kg][wn + j * 16 + fr][0];
#pragma unroll
            for (int i = 0; i < 4; ++i) {
                acc[i][j] = mfma16(a_h[i], b_h, acc[i][j]);
                acc[i][j] = mfma16(a_l[i], b_h, acc[i][j]);
            }
        }
        __builtin_amdgcn_s_setprio(0);
    };

    // prologue
    LOAD(0);
    STORE(0);
    __syncthreads();

    int cur = 0;
    for (int ks = 0; ks < ksteps; ++ks) {
        LOAD(ks + 1);     // issue next-step global loads (predicated off past end)
        COMPUTE(cur);     // ds_read + MFMA — load latency hides under this
        STORE(cur ^ 1);   // waitcnt(regs) + convert + ds_write
        __syncthreads();  // single barrier per k-step
        cur ^= 1;
    }

    // ---- epilogue: C/D layout col=lane&15, row=(lane>>4)*4+reg ----
#pragma unroll
    for (int i = 0; i < 4; ++i) {
        const int mbase = m0 + wm + i * 16 + kg * 4;
#pragma unroll
        for (int r2 = 0; r2 < 4; ++r2) {
            const int mm = mbase + r2;
            if (mm >= M) continue;
            float bias = 0.f;
            if (MODE == 1)
                bias = (mm < FOUT) ? P2[(size_t)z * FOUT + mm]
                                   : P3[(size_t)z * FOUT + (mm - FOUT)];
#pragma unroll
            for (int j = 0; j < 4; ++j) {
                const int nn = n0 + wn + j * 16 + fr;
                if (nn < N) {
                    float v = acc[i][j][r2] + bias;
                    if (MODE == 2) ((float*)Cp)[(size_t)mm * ldc + nn] = v;
                    else           ((ushort*)Cp)[(size_t)mm * ldc + nn] = f16bits(tof16(v));
                }
            }
        }
    }
}

// ---------------- T1: X[b'][f][c](u16) -> XT[c][f][b'](u16) ----------------
__global__ void transpose_bc(const ushort* __restrict__ in, ushort* __restrict__ out, int Bc) {
    __shared__ ushort tile[32][34];
    int f = blockIdx.x;
    int c0 = blockIdx.y * 32, b0 = blockIdx.z * 32;
    int tx = threadIdx.x, ty = threadIdx.y;
#pragma unroll
    for (int j = 0; j < 4; ++j) {
        int bb = b0 + ty + j * 8, cc = c0 + tx;
        if (bb < Bc && cc < CH)
            tile[ty + j * 8][tx] = in[(size_t)bb * KR * CH + (size_t)f * CH + cc];
    }
    __syncthreads();
#pragma unroll
    for (int j = 0; j < 4; ++j) {
        int cc = c0 + ty + j * 8, bb = b0 + tx;
        if (cc < CH && bb < Bc)
            out[(size_t)cc * KR * Bc + (size_t)f * Bc + bb] = tile[tx][ty + j * 8];
    }
}

// ---------------- T3: outT[c][t][b'](f32) -> out[b0+b'][t][c], de-standardize ----------------
__global__ void transpose_out(const float* __restrict__ outT,
                              const float* __restrict__ mean_bc,
                              const float* __restrict__ stdev_bc,
                              float* __restrict__ out, int b0, int Bc) {
    __shared__ float tile[32][33];
    int t = blockIdx.x;
    int c0 = blockIdx.y * 32, bb0 = blockIdx.z * 32;
    int tx = threadIdx.x, ty = threadIdx.y;
#pragma unroll
    for (int j = 0; j < 4; ++j) {
        int cc = c0 + ty + j * 8, bl = bb0 + tx;
        if (cc < CH && bl < Bc)
            tile[ty + j * 8][tx] = outT[(size_t)cc * SEQ * Bc + (size_t)t * Bc + bl];
    }
    __syncthreads();
#pragma unroll
    for (int j = 0; j < 4; ++j) {
        int cc = c0 + tx, bl = bb0 + ty + j * 8;
        if (cc < CH && bl < Bc) {
            int b = b0 + bl;
            size_t si = (size_t)b * CH + cc;
            out[(size_t)b * SEQ * CH + (size_t)t * CH + cc] =
                tile[tx][ty + j * 8] * stdev_bc[si] + mean_bc[si];
        }
    }
}

// ---------------- launch ----------------
extern "C" void kernel_launch(void* const* d_in, const int* in_sizes, int n_in,
                              void* d_out, int out_size, void* d_ws, size_t ws_size,
                              hipStream_t stream) {
    const float* x_enc = (const float*)d_in[0];
    const float* Wr = (const float*)d_in[4];
    const float* Wi = (const float*)d_in[5];
    const float* br = (const float*)d_in[6];
    const float* bi = (const float*)d_in[7];
    float* out = (float*)d_out;

    auto alb = [](size_t x) { return (x + 255) & ~(size_t)255; };  // 256B align
    const size_t fixedB = 2 * alb((size_t)KR * SEQ * 2)      // Dh, Dl
                        + 2 * alb((size_t)SEQ * MC * 2)      // Gh, Gl
                        + 3 * alb((size_t)NBATCH * CH * 4);  // mean, rstd, std

    int Bc = NBATCH;
    while (Bc > 1) {
        size_t perB = 2 * alb((size_t)Bc * KR * CH * 2)      // X, XT (f16)
                    + alb((size_t)CH * MC * Bc * 2)          // F (f16)
                    + alb((size_t)CH * SEQ * Bc * 4);        // outT (f32)
        if (fixedB + perB <= ws_size) break;
        Bc >>= 1;
    }

    char* wsb = (char*)d_ws;
    size_t off = 0;
    auto take = [&](size_t bytes) { size_t o = off; off += alb(bytes); return o; };
    f16*    Dh   = (f16*)(wsb + take((size_t)KR * SEQ * 2));
    f16*    Dl   = (f16*)(wsb + take((size_t)KR * SEQ * 2));
    f16*    Gh   = (f16*)(wsb + take((size_t)SEQ * MC * 2));
    f16*    Gl   = (f16*)(wsb + take((size_t)SEQ * MC * 2));
    float*  Mean = (float*)(wsb + take((size_t)NBATCH * CH * 4));
    float*  Rstd = (float*)(wsb + take((size_t)NBATCH * CH * 4));
    float*  Stdv = (float*)(wsb + take((size_t)NBATCH * CH * 4));
    ushort* Xb   = (ushort*)(wsb + take((size_t)Bc * KR * CH * 2));
    ushort* XT   = (ushort*)(wsb + take((size_t)Bc * KR * CH * 2));
    ushort* Fb   = (ushort*)(wsb + take((size_t)CH * MC * Bc * 2));
    float*  OT   = (float*)(wsb + take((size_t)CH * SEQ * Bc * 4));

    init_dmat<<<(KR * SEQ + 255) / 256, 256, 0, stream>>>(Dh, Dl);
    init_gmat<<<(SEQ * MC + 255) / 256, 256, 0, stream>>>(Gh, Gl);
    stats_kernel<<<(NBATCH * CH + 255) / 256, 256, 0, stream>>>(x_enc, Mean, Rstd, Stdv);

    const int nch = NBATCH / Bc;
    for (int ci = 0; ci < nch; ++ci) {
        int b0 = ci * Bc;

        {   // rfft
            int gx = (KR + 127) / 128, gy = (CH + 127) / 128;
            int nb = gx * gy * Bc;
            gemm_mfma<0><<<nb, 256, 0, stream>>>(Dh, Dl, (const void*)x_enc, (void*)Xb,
                                                 Mean, Rstd, nullptr, nullptr,
                                                 Bc, b0, gx, gy);
        }

        dim3 gT1(KR, (CH + 31) / 32, (Bc + 31) / 32);
        transpose_bc<<<gT1, dim3(32, 8), 0, stream>>>(Xb, XT, Bc);

        {   // mix
            int gx = (MC + 127) / 128, gy = (Bc + 127) / 128;
            int nb = gx * gy * CH;
            gemm_mfma<1><<<nb, 256, 0, stream>>>(nullptr, nullptr, (const void*)XT, (void*)Fb,
                                                 Wr, Wi, br, bi,
                                                 Bc, 0, gx, gy);
        }

        {   // irfft
            int gx = (SEQ + 127) / 128, gy = (Bc + 127) / 128;
            int nb = gx * gy * CH;
            gemm_mfma<2><<<nb, 256, 0, stream>>>(Gh, Gl, (const void*)Fb, (void*)OT,
                                                 nullptr, nullptr, nullptr, nullptr,
                                                 Bc, 0, gx, gy);
        }

        dim3 gT3(SEQ, (CH + 31) / 32, (Bc + 31) / 32);
        transpose_out<<<gT3, dim3(32, 8), 0, stream>>>(OT, Mean, Stdv, out, b0, Bc);
    }
}